// Round 8
// baseline (287.023 us; speedup 1.0000x reference)
//
#include <hip/hip_runtime.h>

// LinearAttention fused pipeline for MI355X (gfx950) — round 12.
// r11 model: K2 block time = E(~40us entry) + T(~2.7us)*tiles; grid 1024 at
// 2 blocks/CU ran 2 rounds -> 2 entries -> regression. r12 makes the small-
// block geometry deliver ONE round at 4 blocks/CU: ctxT LDS buffer deleted
// (each thread computes its 2 ae fragments straight into registers from
// ctx_u/Zsum — bit-identical values), K2 LDS 44->33.8 KB -> 4 blocks/CU,
// grid 1024 all-resident, 16 waves/CU (2x r8's TLP). launch_bounds(256,4)
// caps VGPR at 128; xr restructured to never co-live with accumulators
// (tile t+1 loads issued after b2, converted after the exp/softmax stretch).
// K1 = r8's proven version untouched (TPB=4, grid 512, 2/CU).
//
// ws: ctx_u[32][4][32][32] f32 | Z[32][128] f32 | stats[32][2] f32 | wb 4x16384 bf16

#define B_   32
#define C_   128
#define N_   4096
#define H_   4
#define D_   32
#define HID  128
#define NB   64
#define TPB  4        // n-tiles per block (K1)
#define NSTRIP 16     // strips per batch, K1
#define TPB2   2      // n-tiles per block (K2)
#define NSTRIP2 32    // strips per batch, K2
#define STV  72       // ek/v row stride (shorts)
#define STA  136      // eqT/attnT row stride (shorts)
#define SCALE 0.1767766952966369f
#define EPS  1e-5f

typedef __attribute__((ext_vector_type(8))) short short8;
typedef __attribute__((ext_vector_type(4))) short short4v;
typedef __attribute__((ext_vector_type(4))) float floatx4;

__device__ __forceinline__ short f2bf(float f) {   // RNE fp32 -> bf16
  unsigned u = __float_as_uint(f);
  u += 0x7FFFu + ((u >> 16) & 1u);
  return (short)(u >> 16);
}

// load the wave's c-quarter of x tile tt into registers (32 scalar f32,
// each instr coalesces 4 rows x 64B across the wave)
#define XLOAD(tt)                                                        \
  _Pragma("unroll")                                                      \
  for (int nt = 0; nt < 4; ++nt)                                         \
    _Pragma("unroll")                                                    \
    for (int j = 0; j < 8; ++j)                                          \
      xr[nt][j] = xw[(size_t)j * N_ + (size_t)(tt) * NB + nt * 16];

// convert + write this wave's 4 fragments (lane-linear b128, conflict-free)
#define XCVT(fragbuf)                                                    \
  _Pragma("unroll")                                                      \
  for (int nt = 0; nt < 4; ++nt) {                                       \
    short8 s;                                                            \
    _Pragma("unroll")                                                    \
    for (int j = 0; j < 8; ++j) s[j] = f2bf(xr[nt][j]);                  \
    *(short8*)&fragbuf[((w * 4 + nt) * 64 + L) * 8] = s;                 \
  }

// ---------------------------------------------------------------- K0: weights -> bf16
__global__ __launch_bounds__(256) void k_wcast(
    const float* __restrict__ Wq, const float* __restrict__ Wk,
    const float* __restrict__ Wv, const float* __restrict__ Wo,
    short* __restrict__ wb) {
  const int i = blockIdx.x * 256 + threadIdx.x;   // 0..16383, 4 elems each
  const float* srcs[4] = {Wq, Wk, Wv, Wo};
#pragma unroll
  for (int m = 0; m < 4; ++m) {
    floatx4 a = ((const floatx4*)srcs[m])[i];
    short4v s = { f2bf(a[0]), f2bf(a[1]), f2bf(a[2]), f2bf(a[3]) };
    ((short4v*)(wb + m * 16384))[i] = s;
  }
}

// ---------------------------------------------------------------- K1: k,v proj + ctx/Z (r8-proven)
__global__ __launch_bounds__(256, 2) void k_kv_ctx(
    const float* __restrict__ x, const short* __restrict__ Wkb,
    const short* __restrict__ Wvb, float* __restrict__ ctx_u,
    float* __restrict__ Zsum) {
  __shared__ short frag[8192];           // 16 KB bf16 fragment tile
  __shared__ short ekbuf[C_ * STV];      // 18 KB
  __shared__ short vbuf [C_ * STV];      // 18 KB
  const int tid = threadIdx.x;
  const int w = tid >> 6, L = tid & 63, l15 = tid & 15, q4 = (tid & 63) >> 4;
  const int b = blockIdx.x / NSTRIP;
  const int strip = blockIdx.x % NSTRIP;
  const float* xw = x + (size_t)b * (C_ * N_) + (size_t)(w * 32 + q4 * 8) * N_
                      + (size_t)(strip * TPB) * NB + l15;

  short8 ak[2][4], av[2][4];
#pragma unroll
  for (int mt = 0; mt < 2; ++mt)
#pragma unroll
    for (int ks = 0; ks < 4; ++ks) {
      ak[mt][ks] = *(const short8*)&Wkb[(w * 32 + mt * 16 + l15) * C_ + ks * 32 + q4 * 8];
      av[mt][ks] = *(const short8*)&Wvb[(w * 32 + mt * 16 + l15) * C_ + ks * 32 + q4 * 8];
    }

  const floatx4 z4 = {0.f, 0.f, 0.f, 0.f};
  floatx4 ca[2][2] = {{z4, z4}, {z4, z4}};   // ctx accumulator across tiles
  float zreg[2][4] = {{0.f,0.f,0.f,0.f},{0.f,0.f,0.f,0.f}};
  float xr[4][8];

  // prologue: tile0 -> regs -> frag; issue tile1 loads
  XLOAD(0)
  XCVT(frag)
  XLOAD(1)

  for (int t = 0; t < TPB; ++t) {
    __syncthreads();   // b1: frag(t) visible

    // ---- k GEMM (acck live only until pack-ek below)
    floatx4 acck[2][4];
#pragma unroll
    for (int mt = 0; mt < 2; ++mt)
#pragma unroll
      for (int nt = 0; nt < 4; ++nt) acck[mt][nt] = z4;
#pragma unroll
    for (int ks = 0; ks < 4; ++ks) {
      short8 Bf[4];
#pragma unroll
      for (int nt = 0; nt < 4; ++nt)
        Bf[nt] = *(const short8*)&frag[((ks * 4 + nt) * 64 + L) * 8];
#pragma unroll
      for (int mt = 0; mt < 2; ++mt)
#pragma unroll
        for (int nt = 0; nt < 4; ++nt)
          acck[mt][nt] = __builtin_amdgcn_mfma_f32_16x16x32_bf16(ak[mt][ks], Bf[nt], acck[mt][nt], 0, 0, 0);
    }

    // exp(k) + Z partial accumulation + pack ek (kills acck)
#pragma unroll
    for (int mt = 0; mt < 2; ++mt)
#pragma unroll
      for (int nt = 0; nt < 4; ++nt)
#pragma unroll
        for (int r = 0; r < 4; ++r)
          acck[mt][nt][r] = __expf(acck[mt][nt][r]);
#pragma unroll
    for (int mt = 0; mt < 2; ++mt)
#pragma unroll
      for (int r = 0; r < 4; ++r)
        zreg[mt][r] += acck[mt][0][r] + acck[mt][1][r] + acck[mt][2][r] + acck[mt][3][r];
#pragma unroll
    for (int mt = 0; mt < 2; ++mt)
#pragma unroll
      for (int nt = 0; nt < 4; ++nt)
#pragma unroll
        for (int r = 0; r < 4; ++r)
          ekbuf[(w * 32 + mt * 16 + q4 * 4 + r) * STV + nt * 16 + l15] = f2bf(acck[mt][nt][r]);

    // ---- v GEMM (accv born after acck dead; re-reads frag, conflict-free)
    floatx4 accv[2][4];
#pragma unroll
    for (int mt = 0; mt < 2; ++mt)
#pragma unroll
      for (int nt = 0; nt < 4; ++nt) accv[mt][nt] = z4;
#pragma unroll
    for (int ks = 0; ks < 4; ++ks) {
      short8 Bf[4];
#pragma unroll
      for (int nt = 0; nt < 4; ++nt)
        Bf[nt] = *(const short8*)&frag[((ks * 4 + nt) * 64 + L) * 8];
#pragma unroll
      for (int mt = 0; mt < 2; ++mt)
#pragma unroll
        for (int nt = 0; nt < 4; ++nt)
          accv[mt][nt] = __builtin_amdgcn_mfma_f32_16x16x32_bf16(av[mt][ks], Bf[nt], accv[mt][nt], 0, 0, 0);
    }
    __syncthreads();   // b2: all frag reads done -> rewrite allowed

    // convert regs (tile t+1) -> frag; issue loads for tile t+2
    if (t + 1 < TPB) {
      XCVT(frag)
      if (t + 2 < TPB) { XLOAD(t + 2) }
    }

    // pack v (wave-local rows, in-wave DS ordering)
#pragma unroll
    for (int mt = 0; mt < 2; ++mt)
#pragma unroll
      for (int nt = 0; nt < 4; ++nt)
#pragma unroll
        for (int r = 0; r < 4; ++r)
          vbuf[(w * 32 + mt * 16 + q4 * 4 + r) * STV + nt * 16 + l15] = f2bf(accv[mt][nt][r]);

    // ctx partial via MFMA (wave-local rows), accumulates across tiles
#pragma unroll
    for (int ks = 0; ks < 2; ++ks) {
      short8 ae[2], be[2];
#pragma unroll
      for (int mt = 0; mt < 2; ++mt)
        ae[mt] = *(const short8*)&ekbuf[(w * 32 + mt * 16 + l15) * STV + ks * 32 + q4 * 8];
#pragma unroll
      for (int nt = 0; nt < 2; ++nt)
        be[nt] = *(const short8*)&vbuf[(w * 32 + nt * 16 + l15) * STV + ks * 32 + q4 * 8];
#pragma unroll
      for (int mt = 0; mt < 2; ++mt)
#pragma unroll
        for (int nt = 0; nt < 2; ++nt)
          ca[mt][nt] = __builtin_amdgcn_mfma_f32_16x16x32_bf16(ae[mt], be[nt], ca[mt][nt], 0, 0, 0);
    }
  }

  // Z: reduce over l15, one atomic per row
#pragma unroll
  for (int mt = 0; mt < 2; ++mt)
#pragma unroll
    for (int r = 0; r < 4; ++r) {
      float s = zreg[mt][r];
      s += __shfl_xor(s, 1); s += __shfl_xor(s, 2);
      s += __shfl_xor(s, 4); s += __shfl_xor(s, 8);
      if (l15 == 0) atomicAdd(&Zsum[b * HID + w * 32 + mt * 16 + q4 * 4 + r], s);
    }

  // ctx atomics (once per block)
  float* cb = &ctx_u[((size_t)b * H_ + w) * (D_ * D_)];
#pragma unroll
  for (int mt = 0; mt < 2; ++mt)
#pragma unroll
    for (int nt = 0; nt < 2; ++nt)
#pragma unroll
      for (int r = 0; r < 4; ++r)
        atomicAdd(&cb[(mt * 16 + q4 * 4 + r) * D_ + nt * 16 + l15], ca[mt][nt][r]);
}

// ---------------------------------------------------------------- K2: q proj + attn + Wo + stats
// TPB2=2, grid 1024, LDS 33.8 KB -> 4 blocks/CU all-resident (one round).
__global__ __launch_bounds__(256, 4) void k_q_attn_o(
    const float* __restrict__ x, const short* __restrict__ Wqb,
    const short* __restrict__ Wob, const float* __restrict__ bo,
    const float* __restrict__ ctx_u, const float* __restrict__ Zsum,
    float* __restrict__ outp, float* __restrict__ stats) {
  __shared__ short frag[8192];        // 16 KB bf16 fragment tile
  __shared__ short qat[NB * STA];     // eq^T then attn^T, 17 KB
  const int tid = threadIdx.x;
  const int w = tid >> 6, L = tid & 63, l15 = tid & 15, q4 = (tid & 63) >> 4;
  const int b = blockIdx.x / NSTRIP2;
  const int strip = blockIdx.x % NSTRIP2;
  const float* xw = x + (size_t)b * (C_ * N_) + (size_t)(w * 32 + q4 * 8) * N_
                      + (size_t)(strip * TPB2) * NB + l15;

  // prologue: tile0 -> regs -> frag (xr dead before accumulators are born)
  float xr[4][8];
  XLOAD(0)
  XCVT(frag)

  // ae fragments straight into registers (bit-identical to the old ctxT
  // path: same ctx_u * rcp(Zsum) product, same f2bf)
  short8 ae[2];
  {
    const float* cbase = ctx_u + (size_t)b * (H_ * D_ * D_) + w * 1024;
    const float* zbase = Zsum + b * HID + w * 32;
#pragma unroll
    for (int mt = 0; mt < 2; ++mt) {
      short8 s;
#pragma unroll
      for (int j = 0; j < 8; ++j) {
        const int d = q4 * 8 + j;
        float v = cbase[d * 32 + mt * 16 + l15] * __builtin_amdgcn_rcpf(zbase[d]);
        s[j] = f2bf(v);
      }
      ae[mt] = s;
    }
  }

  // register-resident A-frags for Wq and Wo
  short8 aq[2][4], ao[2][4];
#pragma unroll
  for (int mt = 0; mt < 2; ++mt)
#pragma unroll
    for (int ks = 0; ks < 4; ++ks) {
      aq[mt][ks] = *(const short8*)&Wqb[(w * 32 + mt * 16 + l15) * C_ + ks * 32 + q4 * 8];
      ao[mt][ks] = *(const short8*)&Wob[(w * 32 + mt * 16 + l15) * HID + ks * 32 + q4 * 8];
    }

  const floatx4 z4 = {0.f, 0.f, 0.f, 0.f};
  float s1 = 0.f, s2 = 0.f;

  for (int t = 0; t < TPB2; ++t) {
    const int n0 = (strip * TPB2 + t) * NB;
    __syncthreads();   // b1: frag(t) visible

    // q = Wq @ x — B-frags are lane-linear ds_read_b128, no converts
    floatx4 acc[2][4];
#pragma unroll
    for (int mt = 0; mt < 2; ++mt)
#pragma unroll
      for (int nt = 0; nt < 4; ++nt) acc[mt][nt] = z4;
#pragma unroll
    for (int ks = 0; ks < 4; ++ks) {
      short8 Bf[4];
#pragma unroll
      for (int nt = 0; nt < 4; ++nt)
        Bf[nt] = *(const short8*)&frag[((ks * 4 + nt) * 64 + L) * 8];
#pragma unroll
      for (int mt = 0; mt < 2; ++mt)
#pragma unroll
        for (int nt = 0; nt < 4; ++nt)
          acc[mt][nt] = __builtin_amdgcn_mfma_f32_16x16x32_bf16(aq[mt][ks], Bf[nt], acc[mt][nt], 0, 0, 0);
    }
    __syncthreads();   // b2: frag reads done -> rewrite allowed

    // issue tile t+1 loads now; convert AFTER the exp/softmax stretch so the
    // load latency hides under VALU work (xr never co-lives with acc peaks)
    if (t + 1 < TPB2) { XLOAD(t + 1) }

    // exp(q); per-column softmax denom via shuffle
#pragma unroll
    for (int mt = 0; mt < 2; ++mt)
#pragma unroll
      for (int nt = 0; nt < 4; ++nt)
#pragma unroll
        for (int r = 0; r < 4; ++r)
          acc[mt][nt][r] = __expf(acc[mt][nt][r]);
    float inv[4];
#pragma unroll
    for (int nt = 0; nt < 4; ++nt) {
      float s = 0.f;
#pragma unroll
      for (int mt = 0; mt < 2; ++mt)
#pragma unroll
        for (int r = 0; r < 4; ++r) s += acc[mt][nt][r];
      s += __shfl_xor(s, 16); s += __shfl_xor(s, 32);
      inv[nt] = SCALE * __builtin_amdgcn_rcpf(s);
    }

    // scaled eq^T into qat (wave-local columns)
#pragma unroll
    for (int mt = 0; mt < 2; ++mt)
#pragma unroll
      for (int nt = 0; nt < 4; ++nt) {
        short4v pk = { f2bf(acc[mt][nt][0] * inv[nt]), f2bf(acc[mt][nt][1] * inv[nt]),
                       f2bf(acc[mt][nt][2] * inv[nt]), f2bf(acc[mt][nt][3] * inv[nt]) };
        *(short4v*)&qat[(nt * 16 + l15) * STA + w * 32 + mt * 16 + q4 * 4] = pk;
      }

    // convert tile t+1 into frag (before b1 of next iter)
    if (t + 1 < TPB2) { XCVT(frag) }

    // attn: out[e][n] = sum_d ctx[e][d] * eq[d][n]  (ae from registers)
    {
      floatx4 aacc[2][4];
#pragma unroll
      for (int mt = 0; mt < 2; ++mt)
#pragma unroll
        for (int nt = 0; nt < 4; ++nt) aacc[mt][nt] = z4;
#pragma unroll
      for (int nt = 0; nt < 4; ++nt) {
        short8 bq = *(const short8*)&qat[(nt * 16 + l15) * STA + w * 32 + q4 * 8];
#pragma unroll
        for (int mt = 0; mt < 2; ++mt)
          aacc[mt][nt] = __builtin_amdgcn_mfma_f32_16x16x32_bf16(ae[mt], bq, aacc[mt][nt], 0, 0, 0);
      }
      // attn^T over eq^T (same wave-local columns)
#pragma unroll
      for (int nt = 0; nt < 4; ++nt)
#pragma unroll
        for (int mt = 0; mt < 2; ++mt) {
          short4v pk = { f2bf(aacc[mt][nt][0]), f2bf(aacc[mt][nt][1]),
                         f2bf(aacc[mt][nt][2]), f2bf(aacc[mt][nt][3]) };
          *(short4v*)&qat[(nt * 16 + l15) * STA + w * 32 + mt * 16 + q4 * 4] = pk;
        }
    }
    __syncthreads();   // b3: attn^T visible to all waves

    // out_pre = Wo @ attn + bo
    floatx4 oacc[2][4];
#pragma unroll
    for (int mt = 0; mt < 2; ++mt)
#pragma unroll
      for (int nt = 0; nt < 4; ++nt) oacc[mt][nt] = z4;
#pragma unroll
    for (int ks = 0; ks < 4; ++ks) {
      short8 bf8[4];
#pragma unroll
      for (int nt = 0; nt < 4; ++nt)
        bf8[nt] = *(const short8*)&qat[(nt * 16 + l15) * STA + ks * 32 + q4 * 8];
#pragma unroll
      for (int mt = 0; mt < 2; ++mt)
#pragma unroll
        for (int nt = 0; nt < 4; ++nt)
          oacc[mt][nt] = __builtin_amdgcn_mfma_f32_16x16x32_bf16(ao[mt][ks], bf8[nt], oacc[mt][nt], 0, 0, 0);
    }

    // epilogue: +bo, store, accumulate stats in registers
#pragma unroll
    for (int mt = 0; mt < 2; ++mt) {
      const int rowbase = w * 32 + mt * 16 + q4 * 4;
      const floatx4 bo4 = *(const floatx4*)&bo[rowbase];
#pragma unroll
      for (int nt = 0; nt < 4; ++nt) {
        const int n = n0 + nt * 16 + l15;
#pragma unroll
        for (int r = 0; r < 4; ++r) {
          float vv = oacc[mt][nt][r] + bo4[r];
          outp[(size_t)b * (C_ * N_) + (size_t)(rowbase + r) * N_ + n] = vv;
          s1 += vv; s2 += vv * vv;
        }
      }
    }
  }

  // stats: wave reduce + one atomic pair per wave
#pragma unroll
  for (int m = 1; m < 64; m <<= 1) {
    s1 += __shfl_xor(s1, m);
    s2 += __shfl_xor(s2, m);
  }
  if ((tid & 63) == 0) {
    atomicAdd(&stats[b * 2 + 0], s1);
    atomicAdd(&stats[b * 2 + 1], s2);
  }
}

// ---------------------------------------------------------------- K3: GroupNorm
__global__ __launch_bounds__(256) void k_gnorm(
    float* __restrict__ outp, const float* __restrict__ stats,
    const float* __restrict__ gnw, const float* __restrict__ gnb) {
  const int b = blockIdx.x >> 6;
  const int blk = blockIdx.x & 63;
  const float M = (float)(C_ * N_);
  const float mu = stats[b * 2 + 0] / M;
  const float var = stats[b * 2 + 1] / M - mu * mu;
  const float rs = rsqrtf(var + EPS);
  floatx4* p = (floatx4*)(outp + (size_t)b * (C_ * N_) + (size_t)blk * 8192);
  const int tid = threadIdx.x;
#pragma unroll
  for (int i = 0; i < 8; ++i) {
    const int idx = tid + i * 256;
    const int fl = blk * 8192 + idx * 4;
    const int c = fl >> 12;
    const float wgt = gnw[c] * rs;
    const float bia = gnb[c] - mu * wgt;
    floatx4 v = p[idx];
    v[0] = v[0] * wgt + bia;
    v[1] = v[1] * wgt + bia;
    v[2] = v[2] * wgt + bia;
    v[3] = v[3] * wgt + bia;
    p[idx] = v;
  }
}

// ---------------------------------------------------------------- launch
extern "C" void kernel_launch(void* const* d_in, const int* in_sizes, int n_in,
                              void* d_out, int out_size, void* d_ws, size_t ws_size,
                              hipStream_t stream) {
  (void)in_sizes; (void)n_in; (void)out_size; (void)ws_size;
  const float* x   = (const float*)d_in[0];
  const float* Wq  = (const float*)d_in[1];
  const float* Wk  = (const float*)d_in[2];
  const float* Wv  = (const float*)d_in[3];
  const float* Wo  = (const float*)d_in[4];
  const float* bo  = (const float*)d_in[5];
  const float* gnw = (const float*)d_in[6];
  const float* gnb = (const float*)d_in[7];
  float* outp  = (float*)d_out;
  float* ctx_u = (float*)d_ws;                       // 131072 f
  float* Zsum  = ctx_u + B_ * H_ * D_ * D_;          // 4096 f
  float* stats = Zsum + B_ * HID;                    // 64 f
  short* wb    = (short*)(stats + B_ * 2);           // 4 x 16384 bf16
  const size_t zbytes = (size_t)(B_ * H_ * D_ * D_ + B_ * HID + B_ * 2) * sizeof(float);
  hipMemsetAsync(d_ws, 0, zbytes, stream);
  hipLaunchKernelGGL(k_wcast,    dim3(64),           dim3(256), 0, stream, Wq, Wk, Wv, Wo, wb);
  hipLaunchKernelGGL(k_kv_ctx,   dim3(B_ * NSTRIP),  dim3(256), 0, stream, x, wb + 16384, wb + 32768, ctx_u, Zsum);
  hipLaunchKernelGGL(k_q_attn_o, dim3(B_ * NSTRIP2), dim3(256), 0, stream, x, wb, wb + 49152, bo, ctx_u, Zsum, outp, stats);
  hipLaunchKernelGGL(k_gnorm,    dim3(B_ * 64),      dim3(256), 0, stream, outp, stats, gnw, gnb);
}

// Round 9
// 196.099 us; speedup vs baseline: 1.4637x; 1.4637x over previous
//
#include <hip/hip_runtime.h>

// LinearAttention fused pipeline for MI355X (gfx950) — round 13.
// r12 confirmed (3rd time): this kernel family's register demand (~150-190)
// makes any launch_bounds tighter than (256,2) spill catastrophically; and
// at TPB=4 grid 512 caps residency at 2/CU regardless. r13 stops chasing
// occupancy and shortens the per-tile serial chain at the proven operating
// point (r8 skeleton, (256,2), TPB=4, grid 512):
//  - K2: ctxT LDS deleted; ae fragments built in registers (r12-proven
//    value-identical). Entry work down, LDS 44->49.4 KB incl. dbuf.
//  - K2: double-buffered frag: 3 barriers/tile -> 2 (attn^T publish +
//    qat recycle are the protocol minimum).
//  - K1: fused k+v GEMM restored (one Bf read feeds both MFMAs; ~190 regs
//    < 256 cap) + dbuf frag: 2 barriers/tile -> 1. LDS 68 KB (gfx950
//    allows >64 KB static; r5 ran 68 KB).
// Numerics bit-identical to r8.
//
// ws: ctx_u[32][4][32][32] f32 | Z[32][128] f32 | stats[32][2] f32 | wb 4x16384 bf16

#define B_   32
#define C_   128
#define N_   4096
#define H_   4
#define D_   32
#define HID  128
#define NB   64
#define TPB  4        // n-tiles per block
#define NSTRIP 16     // strips per batch (NSTRIP*TPB*NB == N_)
#define STV  72       // ek/v row stride (shorts)
#define STA  136      // eqT/attnT row stride (shorts)
#define SCALE 0.1767766952966369f
#define EPS  1e-5f

typedef __attribute__((ext_vector_type(8))) short short8;
typedef __attribute__((ext_vector_type(4))) short short4v;
typedef __attribute__((ext_vector_type(4))) float floatx4;

__device__ __forceinline__ short f2bf(float f) {   // RNE fp32 -> bf16
  unsigned u = __float_as_uint(f);
  u += 0x7FFFu + ((u >> 16) & 1u);
  return (short)(u >> 16);
}

// load the wave's c-quarter of x tile tt into registers (32 scalar f32,
// each instr coalesces 4 rows x 64B across the wave)
#define XLOAD(tt)                                                        \
  _Pragma("unroll")                                                      \
  for (int nt = 0; nt < 4; ++nt)                                         \
    _Pragma("unroll")                                                    \
    for (int j = 0; j < 8; ++j)                                          \
      xr[nt][j] = xw[(size_t)j * N_ + (size_t)(tt) * NB + nt * 16];

// convert + write this wave's 4 fragments (lane-linear b128, conflict-free)
#define XCVT(fragbuf)                                                    \
  _Pragma("unroll")                                                      \
  for (int nt = 0; nt < 4; ++nt) {                                       \
    short8 s;                                                            \
    _Pragma("unroll")                                                    \
    for (int j = 0; j < 8; ++j) s[j] = f2bf(xr[nt][j]);                  \
    *(short8*)&(fragbuf)[((w * 4 + nt) * 64 + L) * 8] = s;               \
  }

// ---------------------------------------------------------------- K0: weights -> bf16
__global__ __launch_bounds__(256) void k_wcast(
    const float* __restrict__ Wq, const float* __restrict__ Wk,
    const float* __restrict__ Wv, const float* __restrict__ Wo,
    short* __restrict__ wb) {
  const int i = blockIdx.x * 256 + threadIdx.x;   // 0..16383, 4 elems each
  const float* srcs[4] = {Wq, Wk, Wv, Wo};
#pragma unroll
  for (int m = 0; m < 4; ++m) {
    floatx4 a = ((const floatx4*)srcs[m])[i];
    short4v s = { f2bf(a[0]), f2bf(a[1]), f2bf(a[2]), f2bf(a[3]) };
    ((short4v*)(wb + m * 16384))[i] = s;
  }
}

// ---------------------------------------------------------------- K1: k,v proj + ctx/Z
// dbuf frag -> ONE barrier per tile; fused k+v GEMM (one Bf read, 2 MFMAs).
__global__ __launch_bounds__(256, 2) void k_kv_ctx(
    const float* __restrict__ x, const short* __restrict__ Wkb,
    const short* __restrict__ Wvb, float* __restrict__ ctx_u,
    float* __restrict__ Zsum) {
  __shared__ short frag[2][8192];        // 2 x 16 KB bf16 fragment tiles
  __shared__ short ekbuf[C_ * STV];      // 18 KB
  __shared__ short vbuf [C_ * STV];      // 18 KB
  const int tid = threadIdx.x;
  const int w = tid >> 6, L = tid & 63, l15 = tid & 15, q4 = (tid & 63) >> 4;
  const int b = blockIdx.x / NSTRIP;
  const int strip = blockIdx.x % NSTRIP;
  const float* xw = x + (size_t)b * (C_ * N_) + (size_t)(w * 32 + q4 * 8) * N_
                      + (size_t)(strip * TPB) * NB + l15;

  short8 ak[2][4], av[2][4];
#pragma unroll
  for (int mt = 0; mt < 2; ++mt)
#pragma unroll
    for (int ks = 0; ks < 4; ++ks) {
      ak[mt][ks] = *(const short8*)&Wkb[(w * 32 + mt * 16 + l15) * C_ + ks * 32 + q4 * 8];
      av[mt][ks] = *(const short8*)&Wvb[(w * 32 + mt * 16 + l15) * C_ + ks * 32 + q4 * 8];
    }

  const floatx4 z4 = {0.f, 0.f, 0.f, 0.f};
  floatx4 ca[2][2] = {{z4, z4}, {z4, z4}};   // ctx accumulator across tiles
  float zreg[2][4] = {{0.f,0.f,0.f,0.f},{0.f,0.f,0.f,0.f}};
  float xr[4][8];

  // prologue: tile0 -> regs -> frag0; issue tile1 loads
  XLOAD(0)
  XCVT(frag[0])
  XLOAD(1)

  for (int t = 0; t < TPB; ++t) {
    __syncthreads();   // frag[t&1] complete from all waves; other buf free

    // fused k+v GEMM: each Bf read feeds both MFMAs
    floatx4 acck[2][4], accv[2][4];
#pragma unroll
    for (int mt = 0; mt < 2; ++mt)
#pragma unroll
      for (int nt = 0; nt < 4; ++nt) { acck[mt][nt] = z4; accv[mt][nt] = z4; }
#pragma unroll
    for (int ks = 0; ks < 4; ++ks) {
      short8 Bf[4];
#pragma unroll
      for (int nt = 0; nt < 4; ++nt)
        Bf[nt] = *(const short8*)&frag[t & 1][((ks * 4 + nt) * 64 + L) * 8];
#pragma unroll
      for (int mt = 0; mt < 2; ++mt)
#pragma unroll
        for (int nt = 0; nt < 4; ++nt) {
          acck[mt][nt] = __builtin_amdgcn_mfma_f32_16x16x32_bf16(ak[mt][ks], Bf[nt], acck[mt][nt], 0, 0, 0);
          accv[mt][nt] = __builtin_amdgcn_mfma_f32_16x16x32_bf16(av[mt][ks], Bf[nt], accv[mt][nt], 0, 0, 0);
        }
    }

    // convert tile t+1 into the OTHER buffer (its readers finished before
    // this tile's barrier); refill xr for t+2
    if (t + 1 < TPB) {
      XCVT(frag[(t + 1) & 1])
      if (t + 2 < TPB) { XLOAD(t + 2) }
    }

    // exp(k) + Z partials + pack ek (wave-local rows, in-wave DS ordering)
#pragma unroll
    for (int mt = 0; mt < 2; ++mt)
#pragma unroll
      for (int nt = 0; nt < 4; ++nt)
#pragma unroll
        for (int r = 0; r < 4; ++r)
          acck[mt][nt][r] = __expf(acck[mt][nt][r]);
#pragma unroll
    for (int mt = 0; mt < 2; ++mt)
#pragma unroll
      for (int r = 0; r < 4; ++r)
        zreg[mt][r] += acck[mt][0][r] + acck[mt][1][r] + acck[mt][2][r] + acck[mt][3][r];
#pragma unroll
    for (int mt = 0; mt < 2; ++mt)
#pragma unroll
      for (int nt = 0; nt < 4; ++nt)
#pragma unroll
        for (int r = 0; r < 4; ++r) {
          ekbuf[(w * 32 + mt * 16 + q4 * 4 + r) * STV + nt * 16 + l15] = f2bf(acck[mt][nt][r]);
          vbuf [(w * 32 + mt * 16 + q4 * 4 + r) * STV + nt * 16 + l15] = f2bf(accv[mt][nt][r]);
        }

    // ctx partial via MFMA (wave-local rows), accumulates across tiles
#pragma unroll
    for (int ks = 0; ks < 2; ++ks) {
      short8 ae[2], be[2];
#pragma unroll
      for (int mt = 0; mt < 2; ++mt)
        ae[mt] = *(const short8*)&ekbuf[(w * 32 + mt * 16 + l15) * STV + ks * 32 + q4 * 8];
#pragma unroll
      for (int nt = 0; nt < 2; ++nt)
        be[nt] = *(const short8*)&vbuf[(w * 32 + nt * 16 + l15) * STV + ks * 32 + q4 * 8];
#pragma unroll
      for (int mt = 0; mt < 2; ++mt)
#pragma unroll
        for (int nt = 0; nt < 2; ++nt)
          ca[mt][nt] = __builtin_amdgcn_mfma_f32_16x16x32_bf16(ae[mt], be[nt], ca[mt][nt], 0, 0, 0);
    }
  }

  // Z: reduce over l15, one atomic per row
#pragma unroll
  for (int mt = 0; mt < 2; ++mt)
#pragma unroll
    for (int r = 0; r < 4; ++r) {
      float s = zreg[mt][r];
      s += __shfl_xor(s, 1); s += __shfl_xor(s, 2);
      s += __shfl_xor(s, 4); s += __shfl_xor(s, 8);
      if (l15 == 0) atomicAdd(&Zsum[b * HID + w * 32 + mt * 16 + q4 * 4 + r], s);
    }

  // ctx atomics (once per block)
  float* cb = &ctx_u[((size_t)b * H_ + w) * (D_ * D_)];
#pragma unroll
  for (int mt = 0; mt < 2; ++mt)
#pragma unroll
    for (int nt = 0; nt < 2; ++nt)
#pragma unroll
      for (int r = 0; r < 4; ++r)
        atomicAdd(&cb[(mt * 16 + q4 * 4 + r) * D_ + nt * 16 + l15], ca[mt][nt][r]);
}

// ---------------------------------------------------------------- K2: q proj + attn + Wo + stats
// dbuf frag + register-ae -> TWO barriers per tile (qat protocol minimum).
__global__ __launch_bounds__(256, 2) void k_q_attn_o(
    const float* __restrict__ x, const short* __restrict__ Wqb,
    const short* __restrict__ Wob, const float* __restrict__ bo,
    const float* __restrict__ ctx_u, const float* __restrict__ Zsum,
    float* __restrict__ outp, float* __restrict__ stats) {
  __shared__ short frag[2][8192];     // 2 x 16 KB bf16 fragment tiles
  __shared__ short qat[NB * STA];     // eq^T then attn^T, 17 KB
  const int tid = threadIdx.x;
  const int w = tid >> 6, L = tid & 63, l15 = tid & 15, q4 = (tid & 63) >> 4;
  const int b = blockIdx.x / NSTRIP;
  const int strip = blockIdx.x % NSTRIP;
  const float* xw = x + (size_t)b * (C_ * N_) + (size_t)(w * 32 + q4 * 8) * N_
                      + (size_t)(strip * TPB) * NB + l15;

  // prologue: tile0 -> regs -> frag0; issue tile1 loads
  float xr[4][8];
  XLOAD(0)
  XCVT(frag[0])
  XLOAD(1)

  // ae fragments straight into registers (value-identical to the old ctxT
  // path: same ctx_u * rcp(Zsum) product, same f2bf) — r12-proven
  short8 ae[2];
  {
    const float* cbase = ctx_u + (size_t)b * (H_ * D_ * D_) + w * 1024;
    const float* zbase = Zsum + b * HID + w * 32;
#pragma unroll
    for (int mt = 0; mt < 2; ++mt) {
      short8 s;
#pragma unroll
      for (int j = 0; j < 8; ++j) {
        const int d = q4 * 8 + j;
        float v = cbase[d * 32 + mt * 16 + l15] * __builtin_amdgcn_rcpf(zbase[d]);
        s[j] = f2bf(v);
      }
      ae[mt] = s;
    }
  }

  // register-resident A-frags for Wq and Wo
  short8 aq[2][4], ao[2][4];
#pragma unroll
  for (int mt = 0; mt < 2; ++mt)
#pragma unroll
    for (int ks = 0; ks < 4; ++ks) {
      aq[mt][ks] = *(const short8*)&Wqb[(w * 32 + mt * 16 + l15) * C_ + ks * 32 + q4 * 8];
      ao[mt][ks] = *(const short8*)&Wob[(w * 32 + mt * 16 + l15) * HID + ks * 32 + q4 * 8];
    }

  const floatx4 z4 = {0.f, 0.f, 0.f, 0.f};
  float s1 = 0.f, s2 = 0.f;

  for (int t = 0; t < TPB; ++t) {
    const int n0 = (strip * TPB + t) * NB;
    __syncthreads();   // barA: frag[t&1] ready (all waves) + qat recycled

    // q = Wq @ x — B-frags are lane-linear ds_read_b128, no converts
    floatx4 acc[2][4];
#pragma unroll
    for (int mt = 0; mt < 2; ++mt)
#pragma unroll
      for (int nt = 0; nt < 4; ++nt) acc[mt][nt] = z4;
#pragma unroll
    for (int ks = 0; ks < 4; ++ks) {
      short8 Bf[4];
#pragma unroll
      for (int nt = 0; nt < 4; ++nt)
        Bf[nt] = *(const short8*)&frag[t & 1][((ks * 4 + nt) * 64 + L) * 8];
#pragma unroll
      for (int mt = 0; mt < 2; ++mt)
#pragma unroll
        for (int nt = 0; nt < 4; ++nt)
          acc[mt][nt] = __builtin_amdgcn_mfma_f32_16x16x32_bf16(aq[mt][ks], Bf[nt], acc[mt][nt], 0, 0, 0);
    }

    // convert tile t+1 into the OTHER buffer; refill xr for t+2
    if (t + 1 < TPB) {
      XCVT(frag[(t + 1) & 1])
      if (t + 2 < TPB) { XLOAD(t + 2) }
    }

    // exp(q); per-column softmax denom via shuffle
#pragma unroll
    for (int mt = 0; mt < 2; ++mt)
#pragma unroll
      for (int nt = 0; nt < 4; ++nt)
#pragma unroll
        for (int r = 0; r < 4; ++r)
          acc[mt][nt][r] = __expf(acc[mt][nt][r]);
    float inv[4];
#pragma unroll
    for (int nt = 0; nt < 4; ++nt) {
      float s = 0.f;
#pragma unroll
      for (int mt = 0; mt < 2; ++mt)
#pragma unroll
        for (int r = 0; r < 4; ++r) s += acc[mt][nt][r];
      s += __shfl_xor(s, 16); s += __shfl_xor(s, 32);
      inv[nt] = SCALE * __builtin_amdgcn_rcpf(s);
    }

    // scaled eq^T into qat (wave-local columns; in-wave DS ordering)
#pragma unroll
    for (int mt = 0; mt < 2; ++mt)
#pragma unroll
      for (int nt = 0; nt < 4; ++nt) {
        short4v pk = { f2bf(acc[mt][nt][0] * inv[nt]), f2bf(acc[mt][nt][1] * inv[nt]),
                       f2bf(acc[mt][nt][2] * inv[nt]), f2bf(acc[mt][nt][3] * inv[nt]) };
        *(short4v*)&qat[(nt * 16 + l15) * STA + w * 32 + mt * 16 + q4 * 4] = pk;
      }

    // attn: out[e][n] = sum_d ctx[e][d] * eq[d][n]  (ae from registers)
    {
      floatx4 aacc[2][4];
#pragma unroll
      for (int mt = 0; mt < 2; ++mt)
#pragma unroll
        for (int nt = 0; nt < 4; ++nt) aacc[mt][nt] = z4;
#pragma unroll
      for (int nt = 0; nt < 4; ++nt) {
        short8 bq = *(const short8*)&qat[(nt * 16 + l15) * STA + w * 32 + q4 * 8];
#pragma unroll
        for (int mt = 0; mt < 2; ++mt)
          aacc[mt][nt] = __builtin_amdgcn_mfma_f32_16x16x32_bf16(ae[mt], bq, aacc[mt][nt], 0, 0, 0);
      }
      // attn^T over eq^T (same wave-local columns)
#pragma unroll
      for (int nt = 0; nt < 4; ++nt)
#pragma unroll
        for (int mt = 0; mt < 2; ++mt) {
          short4v pk = { f2bf(aacc[mt][nt][0]), f2bf(aacc[mt][nt][1]),
                         f2bf(aacc[mt][nt][2]), f2bf(aacc[mt][nt][3]) };
          *(short4v*)&qat[(nt * 16 + l15) * STA + w * 32 + mt * 16 + q4 * 4] = pk;
        }
    }
    __syncthreads();   // barB: attn^T visible to all waves

    // out_pre = Wo @ attn + bo
    floatx4 oacc[2][4];
#pragma unroll
    for (int mt = 0; mt < 2; ++mt)
#pragma unroll
      for (int nt = 0; nt < 4; ++nt) oacc[mt][nt] = z4;
#pragma unroll
    for (int ks = 0; ks < 4; ++ks) {
      short8 bf8[4];
#pragma unroll
      for (int nt = 0; nt < 4; ++nt)
        bf8[nt] = *(const short8*)&qat[(nt * 16 + l15) * STA + ks * 32 + q4 * 8];
#pragma unroll
      for (int mt = 0; mt < 2; ++mt)
#pragma unroll
        for (int nt = 0; nt < 4; ++nt)
          oacc[mt][nt] = __builtin_amdgcn_mfma_f32_16x16x32_bf16(ao[mt][ks], bf8[nt], oacc[mt][nt], 0, 0, 0);
    }

    // epilogue: +bo, store, accumulate stats in registers
#pragma unroll
    for (int mt = 0; mt < 2; ++mt) {
      const int rowbase = w * 32 + mt * 16 + q4 * 4;
      const floatx4 bo4 = *(const floatx4*)&bo[rowbase];
#pragma unroll
      for (int nt = 0; nt < 4; ++nt) {
        const int n = n0 + nt * 16 + l15;
#pragma unroll
        for (int r = 0; r < 4; ++r) {
          float vv = oacc[mt][nt][r] + bo4[r];
          outp[(size_t)b * (C_ * N_) + (size_t)(rowbase + r) * N_ + n] = vv;
          s1 += vv; s2 += vv * vv;
        }
      }
    }
  }

  // stats: wave reduce + one atomic pair per wave
#pragma unroll
  for (int m = 1; m < 64; m <<= 1) {
    s1 += __shfl_xor(s1, m);
    s2 += __shfl_xor(s2, m);
  }
  if ((tid & 63) == 0) {
    atomicAdd(&stats[b * 2 + 0], s1);
    atomicAdd(&stats[b * 2 + 1], s2);
  }
}

// ---------------------------------------------------------------- K3: GroupNorm
__global__ __launch_bounds__(256) void k_gnorm(
    float* __restrict__ outp, const float* __restrict__ stats,
    const float* __restrict__ gnw, const float* __restrict__ gnb) {
  const int b = blockIdx.x >> 6;
  const int blk = blockIdx.x & 63;
  const float M = (float)(C_ * N_);
  const float mu = stats[b * 2 + 0] / M;
  const float var = stats[b * 2 + 1] / M - mu * mu;
  const float rs = rsqrtf(var + EPS);
  floatx4* p = (floatx4*)(outp + (size_t)b * (C_ * N_) + (size_t)blk * 8192);
  const int tid = threadIdx.x;
#pragma unroll
  for (int i = 0; i < 8; ++i) {
    const int idx = tid + i * 256;
    const int fl = blk * 8192 + idx * 4;
    const int c = fl >> 12;
    const float wgt = gnw[c] * rs;
    const float bia = gnb[c] - mu * wgt;
    floatx4 v = p[idx];
    v[0] = v[0] * wgt + bia;
    v[1] = v[1] * wgt + bia;
    v[2] = v[2] * wgt + bia;
    v[3] = v[3] * wgt + bia;
    p[idx] = v;
  }
}

// ---------------------------------------------------------------- launch
extern "C" void kernel_launch(void* const* d_in, const int* in_sizes, int n_in,
                              void* d_out, int out_size, void* d_ws, size_t ws_size,
                              hipStream_t stream) {
  (void)in_sizes; (void)n_in; (void)out_size; (void)ws_size;
  const float* x   = (const float*)d_in[0];
  const float* Wq  = (const float*)d_in[1];
  const float* Wk  = (const float*)d_in[2];
  const float* Wv  = (const float*)d_in[3];
  const float* Wo  = (const float*)d_in[4];
  const float* bo  = (const float*)d_in[5];
  const float* gnw = (const float*)d_in[6];
  const float* gnb = (const float*)d_in[7];
  float* outp  = (float*)d_out;
  float* ctx_u = (float*)d_ws;                       // 131072 f
  float* Zsum  = ctx_u + B_ * H_ * D_ * D_;          // 4096 f
  float* stats = Zsum + B_ * HID;                    // 64 f
  short* wb    = (short*)(stats + B_ * 2);           // 4 x 16384 bf16
  const size_t zbytes = (size_t)(B_ * H_ * D_ * D_ + B_ * HID + B_ * 2) * sizeof(float);
  hipMemsetAsync(d_ws, 0, zbytes, stream);
  hipLaunchKernelGGL(k_wcast,    dim3(64),          dim3(256), 0, stream, Wq, Wk, Wv, Wo, wb);
  hipLaunchKernelGGL(k_kv_ctx,   dim3(B_ * NSTRIP), dim3(256), 0, stream, x, wb + 16384, wb + 32768, ctx_u, Zsum);
  hipLaunchKernelGGL(k_q_attn_o, dim3(B_ * NSTRIP), dim3(256), 0, stream, x, wb, wb + 49152, bo, ctx_u, Zsum, outp, stats);
  hipLaunchKernelGGL(k_gnorm,    dim3(B_ * 64),     dim3(256), 0, stream, outp, stats, gnw, gnb);
}